// Round 10
// baseline (113.561 us; speedup 1.0000x reference)
//
#include <hip/hip_runtime.h>

// VQ layer B=16,D=64,T=8192,E=512 — f16 MFMA prefilter + exact numpy-fp32 windowed refine.
// Frozen exact recipe (r2..r9, absmax 0): s1=pairwise-8; G=seq-k FMA; c2=seq outer;
// key=(s1-2G)+c2 left-assoc; first-index strict-min.
// Round 10: SPLIT rescan into a second kernel. Kernel A: prefilter + epilogue, stores
// per-wave ambiguity ballots (u64) to ws. Kernel B: 4096 one-wave blocks, each rescans
// its ballot's queries and overwrites z_q/z_id. Removes the serial, imbalanced rescan
// (and its 64-reg body) from A's critical path / pre-epilogue barrier.
// ws layout (halves): [0,32768) f16 frags; [32768,33792) c2 float[512]; [33792,+16K) u64 ballots[4096].

constexpr int Dc = 64, Ec = 512, Tc = 8192;
constexpr int QTOT = 131072, ZQ = 8388608;
constexpr int QPB = 256;          // 8 waves x 32 queries
constexpr int NBLK = QTOT / QPB;  // 512

using half8  = __attribute__((ext_vector_type(8))) _Float16;
using f32x16 = __attribute__((ext_vector_type(16))) float;

// prep: (a) 64 slots x 1KB: wsf[(g*4+c)*512 + l*8 + i] = f16( cb[c*16+(l>>5)*8+i][g*32+(l&31)] * 512 )
//       (b) c2 numpy-exact (seq outer-axis) -> float[512] at wsf+32768
__global__ void vq_prep(const float* __restrict__ cbfull, const int* __restrict__ cbidx,
                        _Float16* __restrict__ wsf) {
    int tid = blockIdx.x * 256 + threadIdx.x;
    const float* cb = cbfull + (size_t)(cbidx[0] & 3) * (Dc * Ec);
    if (tid < 512) {
        float c = cb[tid];
        float a = __fmul_rn(c, c);
        for (int d = 1; d < Dc; ++d) { c = cb[d * Ec + tid]; a = __fadd_rn(a, __fmul_rn(c, c)); }
        ((float*)(wsf + 32768))[tid] = a;
    }
    if (tid >= 4096) return;
    int l = tid & 63, c = (tid >> 6) & 3, g = tid >> 8;
    int n = g * 32 + (l & 31);
    int kbase = c * 16 + (l >> 5) * 8;
    _Float16* dst = wsf + (size_t)(g * 4 + c) * 512 + l * 8;
    #pragma unroll
    for (int i = 0; i < 8; ++i)
        dst[i] = (_Float16)(cb[(kbase + i) * Ec + n] * 512.0f);
}

__global__ __launch_bounds__(512) void vq_main(
    const float* __restrict__ z, const float* __restrict__ cbfull,
    const int* __restrict__ cbidx, _Float16* __restrict__ wsf,
    float* __restrict__ out) {
    __shared__ __attribute__((aligned(16))) _Float16 s_frag[32768];  // 64KB
    __shared__ float s_c2[Ec];
    __shared__ unsigned s_w[QPB];
    __shared__ int s_idx[QPB];

    const int tid = threadIdx.x;
    const int lane = tid & 63;
    const int wave = __builtin_amdgcn_readfirstlane(tid >> 6);  // 0..7 (SGPR)
    const int col = lane & 31, hh = lane >> 5;
    const int q0 = blockIdx.x * QPB;
    const int b = q0 >> 13, t0 = q0 & (Tc - 1);
    const int myq = wave * 32 + col;
    const int t = t0 + myq;

    const int ci = cbidx[0] & 3;
    const float* __restrict__ cb = cbfull + (size_t)ci * (Dc * Ec);

    // query vector -> registers FIRST (HBM latency overlaps staging below)
    float zv[32];
    const float* zp = z + (size_t)b * Dc * Tc + t;
    #pragma unroll
    for (int c = 0; c < 4; ++c)
        #pragma unroll
        for (int i = 0; i < 8; ++i)
            zv[c * 8 + i] = zp[(size_t)(c * 16 + hh * 8 + i) * Tc];

    // one-shot stage: 64KB frags, 8 uint4/thread, coalesced, static indices
    {
        const uint4* src = (const uint4*)wsf;
        uint4* dst = (uint4*)s_frag;
        #pragma unroll
        for (int k = 0; k < 8; ++k) dst[tid + k * 512] = src[tid + k * 512];
    }
    if (tid < 512) s_c2[tid] = ((const float*)(wsf + 32768))[tid];

    // ambiguity window (r9-validated constants)
    float s1p = 0.f;
    #pragma unroll
    for (int e = 0; e < 32; ++e) s1p = __fmaf_rn(zv[e], zv[e], s1p);
    float s1b = (s1p + __shfl_xor(s1p, 32, 64)) * 1.001f + 0.01f;
    float wf = 2.5e-7f * (s1b + 1.f) + 3.2e-5f * sqrtf(s1b) + 1e-5f;
    unsigned w_int = (s1b > 880.f) ? 0x7FFFFFFFu : (unsigned)(wf * 2.147483648e9f) + 512u;
    if (hh == 0) s_w[myq] = w_int;

    // A-frags: u' = -16*z, f16 hi + lo
    half8 uhf[4], ulf[4];
    #pragma unroll
    for (int c = 0; c < 4; ++c)
        #pragma unroll
        for (int i = 0; i < 8; ++i) {
            float f = -16.0f * zv[c * 8 + i];
            _Float16 h = (_Float16)f;
            float hf = (float)h;
            uhf[c][i] = h;
            ulf[c][i] = (_Float16)(f - hf);
        }

    __syncthreads();   // frags + c2 + s_w ready

    // GEMM: 16 groups x {4 ds_read_b128, 8 MFMA f16, pack+min1/min2}; waves independent.
    // kb pre-biased: acc = 4096*(c2 - 2*z.c + 3) in [2^13,2^14) (s1<=880 guard) -> pack acc bits directly.
    unsigned m1[16], m2[16];
    #pragma unroll
    for (int r = 0; r < 16; ++r) { m1[r] = 0xFFFFFFFFu; m2[r] = 0xFFFFFFFFu; }

    #pragma unroll 2
    for (int g = 0; g < 16; ++g) {
        const float kb = __fmaf_rn(s_c2[g * 32 + col], 4096.0f, 12288.0f);
        f32x16 acc;
        #pragma unroll
        for (int r = 0; r < 16; ++r) acc[r] = kb;
        #pragma unroll
        for (int c = 0; c < 4; ++c) {
            half8 chf = *(const half8*)(s_frag + (size_t)(g * 4 + c) * 512 + lane * 8);
            acc = __builtin_amdgcn_mfma_f32_32x32x16_f16(uhf[c], chf, acc, 0, 0, 0);
            acc = __builtin_amdgcn_mfma_f32_32x32x16_f16(ulf[c], chf, acc, 0, 0, 0);
        }
        const unsigned jj = (unsigned)(g * 32 + col);
        #pragma unroll
        for (int r = 0; r < 16; ++r) {
            unsigned key = (__float_as_uint(acc[r]) << 9) | jj;   // exp fixed -> monotone
            unsigned mx = key > m1[r] ? key : m1[r];
            m1[r] = key < m1[r] ? key : m1[r];
            m2[r] = mx < m2[r] ? mx : m2[r];
        }
    }

    // min1/min2 butterfly across 32 code-cols (register-only)
    #pragma unroll
    for (int st = 1; st < 32; st <<= 1) {
        #pragma unroll
        for (int r = 0; r < 16; ++r) {
            unsigned o1 = __shfl_xor(m1[r], st, 64);
            unsigned o2 = __shfl_xor(m2[r], st, 64);
            unsigned mx = m1[r] > o1 ? m1[r] : o1;
            m1[r] = m1[r] < o1 ? m1[r] : o1;
            m2[r] = m2[r] < o2 ? m2[r] : o2;
            m2[r] = m2[r] < mx ? m2[r] : mx;
        }
    }

    // lane col<16 owns accumulator r=col
    unsigned F1 = 0xFFFFFFFFu, F2 = 0xFFFFFFFFu;
    #pragma unroll
    for (int r = 0; r < 16; ++r) if (col == r) { F1 = m1[r]; F2 = m2[r]; }
    bool amb = false;
    if (col < 16) {
        int row = (col & 3) + 8 * (col >> 2) + 4 * hh;   // verified 32x32 C/D row map
        int Q = wave * 32 + row;
        s_idx[Q] = (int)(F1 & 511u);
        unsigned wq = s_w[Q];
        amb = ((unsigned long long)F2 <= (unsigned long long)F1 + wq);
    }
    // ballot: bit = lane = hh*32+col (col<16 only); kernel B decodes identically
    unsigned long long bal = __ballot(amb);
    if (lane == 0)
        ((unsigned long long*)(wsf + 33792))[blockIdx.x * 8 + wave] = bal;
    __syncthreads();

    // epilogue: wave w owns dims [8w, 8w+8); 256 queries via qh loop
    #pragma unroll
    for (int qh = 0; qh < 4; ++qh) {
        const int ql = qh * 64 + lane;
        const int jj = s_idx[ql];
        const int tt = t0 + ql;
        float* op = out + ((size_t)b * Dc + wave * 8) * Tc + tt;
        #pragma unroll
        for (int dd = 0; dd < 8; ++dd)
            op[(size_t)dd * Tc] = cb[(wave * 8 + dd) * Ec + jj];
        if (wave == 0) out[ZQ + q0 + ql] = (float)jj;
    }
}

// Kernel B: one wave per ballot slot; exact numpy-fp32 rescan, overwrite z_q/z_id.
__global__ __launch_bounds__(64) void vq_rescan(
    const float* __restrict__ z, const float* __restrict__ cbfull,
    const int* __restrict__ cbidx, const _Float16* __restrict__ wsf,
    float* __restrict__ out) {
    const int lane = threadIdx.x;
    unsigned long long mask = ((const unsigned long long*)(wsf + 33792))[blockIdx.x];
    if (mask == 0) return;

    const int ci = cbidx[0] & 3;
    const float* __restrict__ cb = cbfull + (size_t)ci * (Dc * Ec);
    const float* __restrict__ c2g = (const float*)(wsf + 32768);
    const int qbase = (blockIdx.x >> 3) * QPB + (blockIdx.x & 7) * 32;
    const int b = qbase >> 13, tb = qbase & (Tc - 1);

    while (mask) {
        int L = __ffsll(mask) - 1; mask &= mask - 1;
        int r = L & 31, hb = L >> 5;
        int row = (r & 3) + 8 * (r >> 2) + 4 * hb;
        int q = qbase + row, t = tb + row;
        const float* zq = z + (size_t)b * Dc * Tc + t;
        float zr[64];
        #pragma unroll
        for (int d = 0; d < 64; ++d) zr[d] = zq[(size_t)d * Tc];
        float rr[8];
        #pragma unroll
        for (int u = 0; u < 8; ++u) rr[u] = __fmul_rn(zr[u], zr[u]);
        #pragma unroll
        for (int i = 8; i < 64; i += 8)
            #pragma unroll
            for (int u = 0; u < 8; ++u)
                rr[u] = __fadd_rn(rr[u], __fmul_rn(zr[i + u], zr[i + u]));
        float s1 = __fadd_rn(__fadd_rn(__fadd_rn(rr[0], rr[1]), __fadd_rn(rr[2], rr[3])),
                             __fadd_rn(__fadd_rn(rr[4], rr[5]), __fadd_rn(rr[6], rr[7])));
        float bk = __int_as_float(0x7f800000);
        int bj = 0;
        for (int u = 0; u < 8; ++u) {
            int j = u * 64 + lane;
            float G = 0.f;
            #pragma unroll
            for (int d = 0; d < 64; ++d) G = __fmaf_rn(zr[d], cb[d * Ec + j], G);
            float key = __fadd_rn(__fsub_rn(s1, __fmul_rn(2.0f, G)), c2g[j]);
            if (key < bk) { bk = key; bj = j; }
        }
        #pragma unroll
        for (int m = 1; m < 64; m <<= 1) {
            float pk = __shfl_xor(bk, m, 64);
            int pj = __shfl_xor(bj, m, 64);
            if (pk < bk || (pk == bk && pj < bj)) { bk = pk; bj = pj; }
        }
        // overwrite: lane d writes dim d (bj uniform across lanes after reduce)
        out[((size_t)b * Dc + lane) * Tc + t] = cb[lane * Ec + bj];
        if (lane == 0) out[ZQ + q] = (float)bj;
    }
}

extern "C" void kernel_launch(void* const* d_in, const int* in_sizes, int n_in,
                              void* d_out, int out_size, void* d_ws, size_t ws_size,
                              hipStream_t stream) {
    const float* z = (const float*)d_in[0];
    const float* cbfull = (const float*)d_in[1];
    const int* cbidx = (const int*)d_in[2];
    _Float16* wsf = (_Float16*)d_ws;
    float* out = (float*)d_out;

    hipLaunchKernelGGL(vq_prep, dim3(16), dim3(256), 0, stream, cbfull, cbidx, wsf);
    hipLaunchKernelGGL(vq_main, dim3(NBLK), dim3(512), 0, stream, z, cbfull, cbidx, wsf, out);
    hipLaunchKernelGGL(vq_rescan, dim3(NBLK * 8), dim3(64), 0, stream, z, cbfull, cbidx, wsf, out);
}